// Round 9
// baseline (193.049 us; speedup 1.0000x reference)
//
#include <hip/hip_runtime.h>
#include <stdint.h>

#define N_NODES 50000
#define N_EDGES 800000
#define IN_F 128
#define HID_F 128
#define OUT_F 128
#define CAT_F 256
#define N_STRIPS 3125  // 50000 / 16 rows per wave-strip

#define NB 256      // edge partition blocks
#define CHUNK 3136  // edges per partition (int4-aligned; 256*3136 >= 800000)
#define NBUCK 3125  // 16-node buckets (50000/16 exact)
#define BCAP 384    // per-bucket record slots (mean 256, +8 sigma; P(ovf)~1e-14)

typedef __bf16 bf16x8 __attribute__((ext_vector_type(8)));
typedef float f32x4 __attribute__((ext_vector_type(4)));

__device__ __forceinline__ uint32_t f2b(float f) {
  uint32_t u = __float_as_uint(f);
  return (u + 0x7fffu + ((u >> 16) & 1u)) >> 16;  // RNE
}

// ---- K1: fused  [0,NB): per-partition bucket histogram | [NB,..): h/Qw/Ww -> bf16
__global__ void __launch_bounds__(256) prep_hist_kernel(
    const int* __restrict__ dst, int* __restrict__ G, const float* __restrict__ h,
    const float* __restrict__ Qw, const float* __restrict__ Ww, uint16_t* __restrict__ hB,
    uint16_t* __restrict__ QwB, uint16_t* __restrict__ WwB) {
  if (blockIdx.x < NB) {
    __shared__ int hist[NBUCK];  // 12.5 KB
    for (int k = threadIdx.x; k < NBUCK; k += 256) hist[k] = 0;
    __syncthreads();
    int b = blockIdx.x;
    int base = b * CHUNK;
    int end = (base + CHUNK < N_EDGES) ? (base + CHUNK) : N_EDGES;
    for (int i4 = base / 4 + threadIdx.x; i4 * 4 < end; i4 += 256) {
      int4 d4 = ((const int4*)dst)[i4];  // CHUNK, N_EDGES divisible by 4
      atomicAdd(&hist[d4.x >> 4], 1);
      atomicAdd(&hist[d4.y >> 4], 1);
      atomicAdd(&hist[d4.z >> 4], 1);
      atomicAdd(&hist[d4.w >> 4], 1);
    }
    __syncthreads();
    for (int k = threadIdx.x; k < NBUCK; k += 256) G[k * NB + b] = hist[k];
  } else {
    const int TOT4 = (N_NODES * IN_F + HID_F * IN_F + OUT_F * CAT_F) / 4;  // 1612288
    int i4 = (blockIdx.x - NB) * 256 + threadIdx.x;
    if (i4 >= TOT4) return;
    int base = i4 * 4;
    const float* src;
    uint16_t* dstp;
    int off;
    if (base < N_NODES * IN_F) {
      src = h; dstp = hB; off = base;
    } else if (base < N_NODES * IN_F + HID_F * IN_F) {
      src = Qw; dstp = QwB; off = base - N_NODES * IN_F;
    } else {
      src = Ww; dstp = WwB; off = base - N_NODES * IN_F - HID_F * IN_F;
    }
    float4 v = *(const float4*)(src + off);
    ushort4 o;
    o.x = (uint16_t)f2b(v.x); o.y = (uint16_t)f2b(v.y);
    o.z = (uint16_t)f2b(v.z); o.w = (uint16_t)f2b(v.w);
    *(ushort4*)(dstp + off) = o;
  }
}

// ---- K2: per-bucket exclusive scan over its NB=256 partition counts (one wave/bucket).
// Writes within-bucket offsets Gs and bucket totals Btot. No global base scan needed:
// rec uses fixed per-bucket capacity BCAP.
__global__ void __launch_bounds__(256) bucket_scan_kernel(const int* __restrict__ G,
                                                          int* __restrict__ Gs,
                                                          int* __restrict__ Btot) {
  int w = (blockIdx.x * 256 + (int)threadIdx.x) >> 6;  // bucket id
  if (w >= NBUCK) return;
  int lane = threadIdx.x & 63;
  int4 v = *(const int4*)(G + (size_t)w * NB + lane * 4);
  int s = v.x + v.y + v.z + v.w;
  int inc = s;
#pragma unroll
  for (int d = 1; d < 64; d <<= 1) {
    int x = __shfl_up(inc, d, 64);
    if (lane >= d) inc += x;
  }
  int exc = inc - s;
  int4 o;
  o.x = exc;
  o.y = exc + v.x;
  o.z = exc + v.x + v.y;
  o.w = exc + v.x + v.y + v.z;
  *(int4*)(Gs + (size_t)w * NB + lane * 4) = o;
  if (lane == 63) Btot[w] = inc;
}

// ---- GEMM1 body: hq = bf16(hB @ Qw^T + Qb), one wave per 16-row strip
__device__ __forceinline__ void gemm1_body(int gb, const uint16_t* __restrict__ hB,
                                           const uint16_t* __restrict__ QwB,
                                           const float* __restrict__ Qb,
                                           uint16_t* __restrict__ hqB) {
  int wave = (gb * 256 + (int)threadIdx.x) >> 6;
  if (wave >= N_STRIPS) return;
  int lane = threadIdx.x & 63;
  int r = lane & 15, qd = lane >> 4;
  int row0 = wave * 16;
  f32x4 acc[8];
#pragma unroll
  for (int t = 0; t < 8; ++t) acc[t] = (f32x4){0.f, 0.f, 0.f, 0.f};
  const uint16_t* aRow = hB + (size_t)(row0 + r) * IN_F + qd * 8;
#pragma unroll
  for (int kt = 0; kt < 4; ++kt) {
    bf16x8 a = *(const bf16x8*)(aRow + kt * 32);
#pragma unroll
    for (int t = 0; t < 8; ++t) {
      bf16x8 b = *(const bf16x8*)(QwB + (t * 16 + r) * IN_F + kt * 32 + qd * 8);
      acc[t] = __builtin_amdgcn_mfma_f32_16x16x32_bf16(a, b, acc[t], 0, 0, 0);
    }
  }
#pragma unroll
  for (int t = 0; t < 8; ++t) {
    float qb = Qb[t * 16 + r];
#pragma unroll
    for (int rr = 0; rr < 4; ++rr) {
      int m = row0 + qd * 4 + rr;
      hqB[(size_t)m * HID_F + t * 16 + r] = (uint16_t)f2b(acc[t][rr] + qb);
    }
  }
}

// ---- K3: fused  [0,NB): LDS-cursor scatter into fixed-capacity buckets | [NB,..): gemm1
__global__ void __launch_bounds__(256) scatter_gemm1_kernel(
    const int* __restrict__ dst, const int* __restrict__ src, const float* __restrict__ ppr,
    const int* __restrict__ Gs, int2* __restrict__ rec, const uint16_t* __restrict__ hB,
    const uint16_t* __restrict__ QwB, const float* __restrict__ Qb,
    uint16_t* __restrict__ hqB) {
  if (blockIdx.x < NB) {
    __shared__ int cursor[NBUCK];  // within-bucket cursors for this partition
    int b = blockIdx.x;
    for (int k = threadIdx.x; k < NBUCK; k += 256) cursor[k] = Gs[(size_t)k * NB + b];
    __syncthreads();
    int base = b * CHUNK;
    int end = (base + CHUNK < N_EDGES) ? (base + CHUNK) : N_EDGES;
    for (int i4 = base / 4 + threadIdx.x; i4 * 4 < end; i4 += 256) {
      int4 d4 = ((const int4*)dst)[i4];
      int4 s4 = ((const int4*)src)[i4];
      float4 w4 = ((const float4*)ppr)[i4];
      int bid, p;
      bid = d4.x >> 4;
      p = atomicAdd(&cursor[bid], 1);
      if (p < BCAP) rec[bid * BCAP + p] = make_int2(s4.x | ((d4.x & 15) << 20), __float_as_int(w4.x));
      bid = d4.y >> 4;
      p = atomicAdd(&cursor[bid], 1);
      if (p < BCAP) rec[bid * BCAP + p] = make_int2(s4.y | ((d4.y & 15) << 20), __float_as_int(w4.y));
      bid = d4.z >> 4;
      p = atomicAdd(&cursor[bid], 1);
      if (p < BCAP) rec[bid * BCAP + p] = make_int2(s4.z | ((d4.z & 15) << 20), __float_as_int(w4.z));
      bid = d4.w >> 4;
      p = atomicAdd(&cursor[bid], 1);
      if (p < BCAP) rec[bid * BCAP + p] = make_int2(s4.w | ((d4.w & 15) << 20), __float_as_int(w4.w));
    }
  } else {
    gemm1_body(blockIdx.x - NB, hB, QwB, Qb, hqB);
  }
}

// ---- K4: fused aggregation + GEMM2. Block (256 thr, 4 waves) owns 16 nodes.
// P1: records -> registers + LDS 16-counter histogram. P2: 16-scan. P3: node-sorted
// LDS scatter. P4: one 16-lane sub per node, 4-deep gather batches, register acc.
// P5: gemm2 rows [g*16,g*16+16), N split across the 4 waves (2 acc tiles each),
// cross-wave L2-norm via LDS.
__global__ void __launch_bounds__(256) agg_gemm2_kernel(
    const uint16_t* __restrict__ hqB, const int2* __restrict__ rec,
    const int* __restrict__ Btot, const uint16_t* __restrict__ hB,
    const uint16_t* __restrict__ WwB, const float* __restrict__ Wb,
    float* __restrict__ out) {
  __shared__ int2 srec[BCAP];     // 3.0 KB
  __shared__ uint4 hagg[16][17];  // 4.3 KB (pad 16->17 breaks stride conflicts)
  __shared__ float ssW[4][16];
  __shared__ int hist[16];
  __shared__ int noff[17];
  __shared__ int cur[16];
  int g = blockIdx.x;
  int t = threadIdx.x;
  if (t < 16) hist[t] = 0;
  __syncthreads();

  int len = Btot[g];
  len = (len < BCAP) ? len : BCAP;

  // P1: load to registers + histogram
  int2 rc[2];
#pragma unroll
  for (int k = 0; k < 2; ++k) {
    int i = t + k * 256;
    if (i < len) {
      rc[k] = rec[g * BCAP + i];
      atomicAdd(&hist[rc[k].x >> 20], 1);
    }
  }
  __syncthreads();

  // P2: exclusive scan of 16 counters (lanes 0..15 of wave 0)
  if (t < 16) {
    int v = hist[t];
    int inc = v;
#pragma unroll
    for (int d = 1; d < 16; d <<= 1) {
      int x = __shfl_up(inc, d, 64);
      if (t >= d) inc += x;
    }
    noff[t] = inc - v;
    cur[t] = inc - v;
    if (t == 15) noff[16] = inc;
  }
  __syncthreads();

  // P3: scatter registers -> node-sorted LDS
#pragma unroll
  for (int k = 0; k < 2; ++k) {
    int i = t + k * 256;
    if (i < len) {
      int p = atomicAdd(&cur[rc[k].x >> 20], 1);
      srec[p] = rc[k];
    }
  }
  __syncthreads();

  // P4: sub-as-node aggregation (sub = t>>4 owns local node nl = t>>4)
  int nl = t >> 4, c = t & 15;
  {
    int nbeg = noff[nl], nend = noff[nl + 1];
    float a[8];
#pragma unroll
    for (int j = 0; j < 8; ++j) a[j] = 0.f;
    float ws = 0.f;
    const uint4* hq4 = (const uint4*)hqB;
    for (int e0 = nbeg; e0 < nend; e0 += 4) {
      int last = nend - 1;
      int2 rr[4];
#pragma unroll
      for (int j = 0; j < 4; ++j) {
        int i = e0 + j;
        rr[j] = srec[(i < last) ? i : last];  // same addr across 16 c-lanes: broadcast
      }
      uint4 u[4];
#pragma unroll
      for (int j = 0; j < 4; ++j) u[j] = hq4[(size_t)(rr[j].x & 0xFFFFF) * 16 + c];
#pragma unroll
      for (int j = 0; j < 4; ++j) {
        float w = (e0 + j < nend) ? __int_as_float(rr[j].y) : 0.f;
        ws += w;
        uint32_t x;
        x = u[j].x;
        a[0] += w * __uint_as_float(x << 16);
        a[1] += w * __uint_as_float(x & 0xffff0000u);
        x = u[j].y;
        a[2] += w * __uint_as_float(x << 16);
        a[3] += w * __uint_as_float(x & 0xffff0000u);
        x = u[j].z;
        a[4] += w * __uint_as_float(x << 16);
        a[5] += w * __uint_as_float(x & 0xffff0000u);
        x = u[j].w;
        a[6] += w * __uint_as_float(x << 16);
        a[7] += w * __uint_as_float(x & 0xffff0000u);
      }
    }
    float dnm = (ws == 0.f) ? 1.f : ws;  // safediv
    float inv = 1.f / dnm;
    uint4 o;
    o.x = f2b(a[0] * inv) | (f2b(a[1] * inv) << 16);
    o.y = f2b(a[2] * inv) | (f2b(a[3] * inv) << 16);
    o.z = f2b(a[4] * inv) | (f2b(a[5] * inv) << 16);
    o.w = f2b(a[6] * inv) | (f2b(a[7] * inv) << 16);
    hagg[nl][c] = o;
  }
  __syncthreads();

  // P5: gemm2, rows row0..row0+16, this wave owns cols [wv*32, wv*32+32)
  int lane = t & 63, wv = t >> 6;
  int row0 = g * 16;
  int r = lane & 15, qd = lane >> 4;
  f32x4 acc[2];
  acc[0] = (f32x4){0.f, 0.f, 0.f, 0.f};
  acc[1] = (f32x4){0.f, 0.f, 0.f, 0.f};
  const uint16_t* aRow = hB + (size_t)(row0 + r) * IN_F + qd * 8;
#pragma unroll
  for (int kt = 0; kt < 8; ++kt) {
    bf16x8 av;
    if (kt < 4) {
      av = *(const bf16x8*)(aRow + kt * 32);
    } else {
      av = *(const bf16x8*)&hagg[r][(kt - 4) * 4 + qd];
    }
#pragma unroll
    for (int t2 = 0; t2 < 2; ++t2) {
      int tt = wv * 2 + t2;
      bf16x8 b = *(const bf16x8*)(WwB + (tt * 16 + r) * CAT_F + kt * 32 + qd * 8);
      acc[t2] = __builtin_amdgcn_mfma_f32_16x16x32_bf16(av, b, acc[t2], 0, 0, 0);
    }
  }
  float lv[2][4];
  float ss4[4] = {0.f, 0.f, 0.f, 0.f};
#pragma unroll
  for (int t2 = 0; t2 < 2; ++t2) {
    float wb = Wb[(wv * 2 + t2) * 16 + r];
#pragma unroll
    for (int rr2 = 0; rr2 < 4; ++rr2) {
      float v = acc[t2][rr2] + wb;
      v = (v >= 0.f) ? v : 0.01f * v;
      lv[t2][rr2] = v;
      ss4[rr2] += v * v;
    }
  }
#pragma unroll
  for (int rr2 = 0; rr2 < 4; ++rr2) {
    float s = ss4[rr2];
    s += __shfl_xor(s, 1);
    s += __shfl_xor(s, 2);
    s += __shfl_xor(s, 4);
    s += __shfl_xor(s, 8);
    ss4[rr2] = s;  // per-row partial over this wave's 32 cols (all r-lanes hold it)
  }
  if (r == 0) {
#pragma unroll
    for (int rr2 = 0; rr2 < 4; ++rr2) ssW[wv][qd * 4 + rr2] = ss4[rr2];
  }
  __syncthreads();
#pragma unroll
  for (int rr2 = 0; rr2 < 4; ++rr2) {
    int row = qd * 4 + rr2;
    float tot = ssW[0][row] + ssW[1][row] + ssW[2][row] + ssW[3][row];
    float nr = sqrtf(tot);
    float inv = (nr == 0.f) ? 1.f : (1.f / nr);
    float* orow = out + (size_t)(row0 + row) * OUT_F;
#pragma unroll
    for (int t2 = 0; t2 < 2; ++t2) orow[(wv * 2 + t2) * 16 + r] = lv[t2][rr2] * inv;
  }
}

extern "C" void kernel_launch(void* const* d_in, const int* in_sizes, int n_in,
                              void* d_out, int out_size, void* d_ws, size_t ws_size,
                              hipStream_t stream) {
  const float* h = (const float*)d_in[0];
  const float* ppr = (const float*)d_in[1];
  const float* Qw = (const float*)d_in[2];
  const float* Qb = (const float*)d_in[3];
  const float* Ww = (const float*)d_in[4];
  const float* Wb = (const float*)d_in[5];
  const int* src = (const int*)d_in[6];
  const int* dst = (const int*)d_in[7];
  float* out = (float*)d_out;

  char* ws = (char*)d_ws;
  size_t o = 0;
  auto alloc = [&](size_t bytes) {
    void* p = ws + o;
    o = (o + bytes + 255) & ~(size_t)255;
    return p;
  };
  uint16_t* hB = (uint16_t*)alloc((size_t)N_NODES * IN_F * 2);    // 12.8 MB
  uint16_t* hqB = (uint16_t*)alloc((size_t)N_NODES * HID_F * 2);  // 12.8 MB
  uint16_t* QwB = (uint16_t*)alloc((size_t)HID_F * IN_F * 2);
  uint16_t* WwB = (uint16_t*)alloc((size_t)OUT_F * CAT_F * 2);
  int* G = (int*)alloc((size_t)NBUCK * NB * 4);   // 3.2 MB
  int* Gs = (int*)alloc((size_t)NBUCK * NB * 4);  // 3.2 MB
  int* Btot = (int*)alloc((size_t)NBUCK * 4);
  int2* rec = (int2*)alloc((size_t)NBUCK * BCAP * 8);  // 9.6 MB
  // total ~41.7 MB; no memset needed (all consumed data fully written each call)

  const int CONV_BLOCKS = ((N_NODES * IN_F + HID_F * IN_F + OUT_F * CAT_F) / 4 + 255) / 256;
  prep_hist_kernel<<<NB + CONV_BLOCKS, 256, 0, stream>>>(dst, G, h, Qw, Ww, hB, QwB, WwB);
  bucket_scan_kernel<<<(NBUCK + 3) / 4, 256, 0, stream>>>(G, Gs, Btot);
  scatter_gemm1_kernel<<<NB + 782, 256, 0, stream>>>(dst, src, ppr, Gs, rec, hB, QwB, Qb,
                                                     hqB);
  agg_gemm2_kernel<<<NBUCK, 256, 0, stream>>>(hqB, rec, Btot, hB, WwB, Wb, out);
}

// Round 10
// 184.857 us; speedup vs baseline: 1.0443x; 1.0443x over previous
//
#include <hip/hip_runtime.h>
#include <stdint.h>

#define N_NODES 50000
#define N_EDGES 800000
#define IN_F 128
#define HID_F 128
#define OUT_F 128
#define CAT_F 256

#define NB 512       // edge partition blocks
#define CHUNK 1568   // edges per partition (int4-aligned; 512*1568 >= 800000)
#define NBUCK 1563   // 32-node buckets (ceil(50000/32))
#define BCAP 640     // per-bucket record slots (mean 512, +5.7 sigma)
#define NCH 16       // partition chunks for the two-level scan (32 partitions each)

typedef __bf16 bf16x8 __attribute__((ext_vector_type(8)));
typedef float f32x4 __attribute__((ext_vector_type(4)));

__device__ __forceinline__ uint32_t f2b(float f) {
  uint32_t u = __float_as_uint(f);
  return (u + 0x7fffu + ((u >> 16) & 1u)) >> 16;  // RNE
}

// ---- K1: fused  [0,NB): per-partition bucket histogram (partition-major, coalesced)
//                 [NB,..): h/Qw/Ww -> bf16
__global__ void __launch_bounds__(256) prep_hist_kernel(
    const int* __restrict__ dst, int* __restrict__ G, const float* __restrict__ h,
    const float* __restrict__ Qw, const float* __restrict__ Ww, uint16_t* __restrict__ hB,
    uint16_t* __restrict__ QwB, uint16_t* __restrict__ WwB) {
  if (blockIdx.x < NB) {
    __shared__ int hist[NBUCK];  // 6.3 KB
    for (int k = threadIdx.x; k < NBUCK; k += 256) hist[k] = 0;
    __syncthreads();
    int b = blockIdx.x;
    int base = b * CHUNK;
    int end = (base + CHUNK < N_EDGES) ? (base + CHUNK) : N_EDGES;
    for (int i4 = base / 4 + threadIdx.x; i4 * 4 < end; i4 += 256) {
      int4 d4 = ((const int4*)dst)[i4];  // CHUNK, N_EDGES divisible by 4
      atomicAdd(&hist[d4.x >> 5], 1);
      atomicAdd(&hist[d4.y >> 5], 1);
      atomicAdd(&hist[d4.z >> 5], 1);
      atomicAdd(&hist[d4.w >> 5], 1);
    }
    __syncthreads();
    for (int k = threadIdx.x; k < NBUCK; k += 256) G[(size_t)b * NBUCK + k] = hist[k];
  } else {
    const int TOT4 = (N_NODES * IN_F + HID_F * IN_F + OUT_F * CAT_F) / 4;  // 1612288
    int i4 = (blockIdx.x - NB) * 256 + threadIdx.x;
    if (i4 >= TOT4) return;
    int base = i4 * 4;
    const float* src;
    uint16_t* dstp;
    int off;
    if (base < N_NODES * IN_F) {
      src = h; dstp = hB; off = base;
    } else if (base < N_NODES * IN_F + HID_F * IN_F) {
      src = Qw; dstp = QwB; off = base - N_NODES * IN_F;
    } else {
      src = Ww; dstp = WwB; off = base - N_NODES * IN_F - HID_F * IN_F;
    }
    float4 v = *(const float4*)(src + off);
    ushort4 o;
    o.x = (uint16_t)f2b(v.x); o.y = (uint16_t)f2b(v.y);
    o.z = (uint16_t)f2b(v.z); o.w = (uint16_t)f2b(v.w);
    *(ushort4*)(dstp + off) = o;
  }
}

// ---- K2a: per-chunk thread-per-bucket scan (coalesced both ways).
// Block set: 7 k-blocks x NCH chunks. Writes intra-chunk prefixes into Gs and
// chunk totals into Ctot[c*NBUCK+k].
__global__ void __launch_bounds__(256) chunk_scan_kernel(const int* __restrict__ G,
                                                         int* __restrict__ Gs,
                                                         int* __restrict__ Ctot) {
  const int KB = (NBUCK + 255) / 256;  // 7
  int k = (blockIdx.x % KB) * 256 + threadIdx.x;
  int c = blockIdx.x / KB;
  if (k >= NBUCK) return;
  int s = 0;
  int b0 = c * (NB / NCH);
#pragma unroll 8
  for (int b = b0; b < b0 + NB / NCH; ++b) {
    int v = G[(size_t)b * NBUCK + k];
    Gs[(size_t)b * NBUCK + k] = s;
    s += v;
  }
  Ctot[(size_t)c * NBUCK + k] = s;
}

// ---- K2b: thread-per-bucket scan over the NCH chunk totals -> Cbase, Btot
__global__ void __launch_bounds__(256) base_scan_kernel(const int* __restrict__ Ctot,
                                                        int* __restrict__ Cbase,
                                                        int* __restrict__ Btot) {
  int k = blockIdx.x * 256 + threadIdx.x;
  if (k >= NBUCK) return;
  int s = 0;
#pragma unroll
  for (int c = 0; c < NCH; ++c) {
    int v = Ctot[(size_t)c * NBUCK + k];
    Cbase[(size_t)c * NBUCK + k] = s;
    s += v;
  }
  Btot[k] = s;
}

// ---- K3: scatter-only. LDS cursors (coalesced init) -> fixed-capacity buckets.
__global__ void __launch_bounds__(256) scatter_kernel(
    const int* __restrict__ dst, const int* __restrict__ src, const float* __restrict__ ppr,
    const int* __restrict__ Gs, const int* __restrict__ Cbase, int2* __restrict__ rec) {
  __shared__ int cursor[NBUCK];  // 6.3 KB
  int b = blockIdx.x;
  int c = b / (NB / NCH);
  for (int k = threadIdx.x; k < NBUCK; k += 256)
    cursor[k] = Gs[(size_t)b * NBUCK + k] + Cbase[(size_t)c * NBUCK + k];
  __syncthreads();
  int base = b * CHUNK;
  int end = (base + CHUNK < N_EDGES) ? (base + CHUNK) : N_EDGES;
  for (int i4 = base / 4 + threadIdx.x; i4 * 4 < end; i4 += 256) {
    int4 d4 = ((const int4*)dst)[i4];
    int4 s4 = ((const int4*)src)[i4];
    float4 w4 = ((const float4*)ppr)[i4];
    int bid, p;
    bid = d4.x >> 5;
    p = atomicAdd(&cursor[bid], 1);
    if (p < BCAP) rec[bid * BCAP + p] = make_int2(s4.x | ((d4.x & 31) << 20), __float_as_int(w4.x));
    bid = d4.y >> 5;
    p = atomicAdd(&cursor[bid], 1);
    if (p < BCAP) rec[bid * BCAP + p] = make_int2(s4.y | ((d4.y & 31) << 20), __float_as_int(w4.y));
    bid = d4.z >> 5;
    p = atomicAdd(&cursor[bid], 1);
    if (p < BCAP) rec[bid * BCAP + p] = make_int2(s4.z | ((d4.z & 31) << 20), __float_as_int(w4.z));
    bid = d4.w >> 5;
    p = atomicAdd(&cursor[bid], 1);
    if (p < BCAP) rec[bid * BCAP + p] = make_int2(s4.w | ((d4.w & 31) << 20), __float_as_int(w4.w));
  }
}

// ---- K4: fused aggregate(raw hB) + Q-apply + GEMM2. Block (256 thr, 4 waves) owns 32 nodes.
// Exploits linearity: h_agg = (Q·(Sum w·h[src]) + (Sum w)·Qb) / den.
// P1-P3: LDS reorder of records. P4: sub-as-node register aggregation of raw hB rows
// (2 nodes per sub) -> s_pre (bf16 LDS) + dinv/bq per node. P5a: Q via MFMA -> hagg LDS.
// P5b: gemm2 (wave-pair splits 128 cols) + leaky_relu + cross-pair L2-norm -> out.
__global__ void __launch_bounds__(256) agg_gemm2_kernel(
    const int2* __restrict__ rec, const int* __restrict__ Btot,
    const uint16_t* __restrict__ hB, const uint16_t* __restrict__ QwB,
    const float* __restrict__ Qb, const uint16_t* __restrict__ WwB,
    const float* __restrict__ Wb, float* __restrict__ out) {
  __shared__ int2 srec[BCAP];     // 5.1 KB
  __shared__ uint4 spre[32][17];  // 8.7 KB  (Sum w*h rows, bf16; pad kills stride conflicts)
  __shared__ uint4 hagg[32][17];  // 8.7 KB
  __shared__ float dinv[32];
  __shared__ float bq[32];
  __shared__ float ssW[4][16];
  __shared__ int hist[32];
  __shared__ int noff[33];
  __shared__ int cur[32];
  int g = blockIdx.x;
  int t = threadIdx.x;
  if (t < 32) hist[t] = 0;
  __syncthreads();

  int len = Btot[g];
  len = (len < BCAP) ? len : BCAP;

  // P1: records -> registers + histogram
  int2 rc[3];
#pragma unroll
  for (int k = 0; k < 3; ++k) {
    int i = t + k * 256;
    if (i < len) {
      rc[k] = rec[g * BCAP + i];
      atomicAdd(&hist[rc[k].x >> 20], 1);
    }
  }
  __syncthreads();

  // P2: exclusive scan of 32 counters (lanes 0..31 of wave 0)
  if (t < 32) {
    int v = hist[t];
    int inc = v;
#pragma unroll
    for (int d = 1; d < 32; d <<= 1) {
      int x = __shfl_up(inc, d, 64);
      if (t >= d) inc += x;
    }
    noff[t] = inc - v;
    cur[t] = inc - v;
    if (t == 31) noff[32] = inc;
  }
  __syncthreads();

  // P3: scatter registers -> node-sorted LDS
#pragma unroll
  for (int k = 0; k < 3; ++k) {
    int i = t + k * 256;
    if (i < len) {
      int p = atomicAdd(&cur[rc[k].x >> 20], 1);
      srec[p] = rc[k];
    }
  }
  __syncthreads();

  // P4: sub-as-node aggregation of raw hB rows; sub handles nodes {sub, sub+16}
  int sub = (t & 63) >> 4, wv = t >> 6, c = t & 15;
  int subg = wv * 4 + sub;  // 16 subs across the block
  const uint4* hb4 = (const uint4*)hB;
#pragma unroll
  for (int ng = 0; ng < 2; ++ng) {
    int nl = subg + ng * 16;
    int nbeg = noff[nl], nend = noff[nl + 1];
    float a[8];
#pragma unroll
    for (int j = 0; j < 8; ++j) a[j] = 0.f;
    float ws = 0.f;
    for (int e0 = nbeg; e0 < nend; e0 += 4) {
      int last = nend - 1;
      int2 rr[4];
#pragma unroll
      for (int j = 0; j < 4; ++j) {
        int i = e0 + j;
        rr[j] = srec[(i < last) ? i : last];  // same addr across 16 c-lanes: broadcast
      }
      uint4 u[4];
#pragma unroll
      for (int j = 0; j < 4; ++j) u[j] = hb4[(size_t)(rr[j].x & 0xFFFFF) * 16 + c];
#pragma unroll
      for (int j = 0; j < 4; ++j) {
        float w = (e0 + j < nend) ? __int_as_float(rr[j].y) : 0.f;
        ws += w;
        uint32_t x;
        x = u[j].x;
        a[0] += w * __uint_as_float(x << 16);
        a[1] += w * __uint_as_float(x & 0xffff0000u);
        x = u[j].y;
        a[2] += w * __uint_as_float(x << 16);
        a[3] += w * __uint_as_float(x & 0xffff0000u);
        x = u[j].z;
        a[4] += w * __uint_as_float(x << 16);
        a[5] += w * __uint_as_float(x & 0xffff0000u);
        x = u[j].w;
        a[6] += w * __uint_as_float(x << 16);
        a[7] += w * __uint_as_float(x & 0xffff0000u);
      }
    }
    uint4 o;
    o.x = f2b(a[0]) | (f2b(a[1]) << 16);
    o.y = f2b(a[2]) | (f2b(a[3]) << 16);
    o.z = f2b(a[4]) | (f2b(a[5]) << 16);
    o.w = f2b(a[6]) | (f2b(a[7]) << 16);
    spre[nl][c] = o;
    if (c == 0) {
      dinv[nl] = (ws == 0.f) ? 1.f : (1.f / ws);
      bq[nl] = (ws == 0.f) ? 0.f : 1.f;
    }
  }
  __syncthreads();

  // P5a: Q-apply: hagg = (spre @ Qw^T) * dinv + bq * Qb  (bf16 MFMA)
  int lane = t & 63;
  int r = lane & 15, qd = lane >> 4;
  int strip = wv >> 1;         // 0 or 1 (16-row strip)
  int colh = wv & 1;           // column half
  {
    f32x4 acc[4];
#pragma unroll
    for (int t2 = 0; t2 < 4; ++t2) acc[t2] = (f32x4){0.f, 0.f, 0.f, 0.f};
#pragma unroll
    for (int kt = 0; kt < 4; ++kt) {
      bf16x8 av = *(const bf16x8*)&spre[strip * 16 + r][kt * 4 + qd];
#pragma unroll
      for (int t2 = 0; t2 < 4; ++t2) {
        int tile = colh * 4 + t2;
        bf16x8 b = *(const bf16x8*)(QwB + (tile * 16 + r) * IN_F + kt * 32 + qd * 8);
        acc[t2] = __builtin_amdgcn_mfma_f32_16x16x32_bf16(av, b, acc[t2], 0, 0, 0);
      }
    }
    uint16_t* hg16 = (uint16_t*)&hagg[0][0];
#pragma unroll
    for (int t2 = 0; t2 < 4; ++t2) {
      int col = (colh * 4 + t2) * 16 + r;
      float qb = Qb[col];
#pragma unroll
      for (int rr2 = 0; rr2 < 4; ++rr2) {
        int row = strip * 16 + qd * 4 + rr2;
        float v = acc[t2][rr2] * dinv[row] + bq[row] * qb;
        hg16[row * 136 + col] = (uint16_t)f2b(v);
      }
    }
  }
  __syncthreads();

  // P5b: gemm2 rows [g*32+strip*16, +16), cols [colh*64, +64)
  int row0 = g * 32 + strip * 16;
  f32x4 acc[4];
#pragma unroll
  for (int t2 = 0; t2 < 4; ++t2) acc[t2] = (f32x4){0.f, 0.f, 0.f, 0.f};
  const uint16_t* aRow = hB + (size_t)(row0 + r) * IN_F + qd * 8;
#pragma unroll
  for (int kt = 0; kt < 8; ++kt) {
    bf16x8 av;
    if (kt < 4) {
      av = *(const bf16x8*)(aRow + kt * 32);
    } else {
      av = *(const bf16x8*)&hagg[strip * 16 + r][(kt - 4) * 4 + qd];
    }
#pragma unroll
    for (int t2 = 0; t2 < 4; ++t2) {
      int tt = colh * 4 + t2;
      bf16x8 b = *(const bf16x8*)(WwB + (tt * 16 + r) * CAT_F + kt * 32 + qd * 8);
      acc[t2] = __builtin_amdgcn_mfma_f32_16x16x32_bf16(av, b, acc[t2], 0, 0, 0);
    }
  }
  float lv[4][4];
  float ss4[4] = {0.f, 0.f, 0.f, 0.f};
#pragma unroll
  for (int t2 = 0; t2 < 4; ++t2) {
    float wb = Wb[(colh * 4 + t2) * 16 + r];
#pragma unroll
    for (int rr2 = 0; rr2 < 4; ++rr2) {
      float v = acc[t2][rr2] + wb;
      v = (v >= 0.f) ? v : 0.01f * v;
      lv[t2][rr2] = v;
      ss4[rr2] += v * v;
    }
  }
#pragma unroll
  for (int rr2 = 0; rr2 < 4; ++rr2) {
    float s = ss4[rr2];
    s += __shfl_xor(s, 1);
    s += __shfl_xor(s, 2);
    s += __shfl_xor(s, 4);
    s += __shfl_xor(s, 8);
    ss4[rr2] = s;  // row partial over this wave's 64 cols
  }
  if (r == 0) {
#pragma unroll
    for (int rr2 = 0; rr2 < 4; ++rr2) ssW[wv][qd * 4 + rr2] = ss4[rr2];
  }
  __syncthreads();
#pragma unroll
  for (int rr2 = 0; rr2 < 4; ++rr2) {
    int rowl = qd * 4 + rr2;
    float tot = ssW[strip * 2][rowl] + ssW[strip * 2 + 1][rowl];
    float nr = sqrtf(tot);
    float inv = (nr == 0.f) ? 1.f : (1.f / nr);
    float* orow = out + (size_t)(row0 + rowl) * OUT_F;
#pragma unroll
    for (int t2 = 0; t2 < 4; ++t2)
      orow[(colh * 4 + t2) * 16 + r] = lv[t2][rr2] * inv;
  }
}

extern "C" void kernel_launch(void* const* d_in, const int* in_sizes, int n_in,
                              void* d_out, int out_size, void* d_ws, size_t ws_size,
                              hipStream_t stream) {
  const float* h = (const float*)d_in[0];
  const float* ppr = (const float*)d_in[1];
  const float* Qw = (const float*)d_in[2];
  const float* Qb = (const float*)d_in[3];
  const float* Ww = (const float*)d_in[4];
  const float* Wb = (const float*)d_in[5];
  const int* src = (const int*)d_in[6];
  const int* dst = (const int*)d_in[7];
  float* out = (float*)d_out;

  char* ws = (char*)d_ws;
  size_t o = 0;
  auto alloc = [&](size_t bytes) {
    void* p = ws + o;
    o = (o + bytes + 255) & ~(size_t)255;
    return p;
  };
  uint16_t* hB = (uint16_t*)alloc((size_t)N_NODES * IN_F * 2);  // 12.8 MB
  uint16_t* QwB = (uint16_t*)alloc((size_t)HID_F * IN_F * 2);
  uint16_t* WwB = (uint16_t*)alloc((size_t)OUT_F * CAT_F * 2);
  int* G = (int*)alloc((size_t)NB * NBUCK * 4);      // 3.2 MB (partition-major)
  int* Gs = (int*)alloc((size_t)NB * NBUCK * 4);     // 3.2 MB
  int* Ctot = (int*)alloc((size_t)NCH * NBUCK * 4);  // 0.1 MB
  int* Cbase = (int*)alloc((size_t)NCH * NBUCK * 4); // 0.1 MB
  int* Btot = (int*)alloc((size_t)NBUCK * 4);
  int2* rec = (int2*)alloc((size_t)NBUCK * BCAP * 8);  // 8.0 MB
  // total ~27.5 MB; no memset needed (all consumed data fully written each call)

  const int KB = (NBUCK + 255) / 256;  // 7
  const int CONV_BLOCKS = ((N_NODES * IN_F + HID_F * IN_F + OUT_F * CAT_F) / 4 + 255) / 256;
  prep_hist_kernel<<<NB + CONV_BLOCKS, 256, 0, stream>>>(dst, G, h, Qw, Ww, hB, QwB, WwB);
  chunk_scan_kernel<<<KB * NCH, 256, 0, stream>>>(G, Gs, Ctot);
  base_scan_kernel<<<KB, 256, 0, stream>>>(Ctot, Cbase, Btot);
  scatter_kernel<<<NB, 256, 0, stream>>>(dst, src, ppr, Gs, Cbase, rec);
  agg_gemm2_kernel<<<NBUCK, 256, 0, stream>>>(rec, Btot, hB, QwB, Qb, WwB, Wb, out);
}